// Round 12
// baseline (211.267 us; speedup 1.0000x reference)
//
#include <hip/hip_runtime.h>
#include <hip/hip_bf16.h>
#include <stdint.h>

#define TOK   256
#define NOBJ  64
#define NDEMO 16
#define BATCH 256
#define SEQ   1105              /* 1 + 16*65 + 64 */
#define NDG   (NDEMO * BATCH)   /* 4096 demo groups */
#define NGRP  (NDG + BATCH)     /* 4352 total groups */
#define NHT   (NGRP * 2)        /* 8704 half-tiles (32 rows each) */
#define NG    8                 /* half-tiles per obj block */
#define OBJ_BLKS   (NHT / NG)   /* 1088 */
#define ACT_BLKS   512
#define INSTR_BLKS 128
#define TOTAL_BLKS (ACT_BLKS + INSTR_BLKS + OBJ_BLKS)

/* stream probe: demo groups 0..2175 as 16-row quarter-tiles */
#define PRB_TILES 8704
#define PRB_NG    16
#define PRB_BLKS  (PRB_TILES / PRB_NG)   /* 544 */

typedef __bf16 bf16x8 __attribute__((ext_vector_type(8)));
typedef float  f32x4  __attribute__((ext_vector_type(4)));

static __device__ __forceinline__ unsigned pack_bf16x2(float a, float b) {
    unsigned ua = __float_as_uint(a);
    unsigned ub = __float_as_uint(b);
    unsigned ra = (ua + 0x7FFFu + ((ua >> 16) & 1u)) >> 16;
    unsigned rb = (ub + 0x7FFFu + ((ub >> 16) & 1u)) >> 16;
    return (ra & 0xFFFFu) | (rb << 16);
}

static __device__ __forceinline__ bf16x8 pack8n(float4 lo, float4 hi) {
    bf16x8 o;
    o[0] = (__bf16)lo.x; o[1] = (__bf16)lo.y;
    o[2] = (__bf16)lo.z; o[3] = (__bf16)lo.w;
    o[4] = (__bf16)hi.x; o[5] = (__bf16)hi.y;
    o[6] = (__bf16)hi.z; o[7] = (__bf16)hi.w;
    return o;
}

// direct global->LDS, 16B per lane (dest linear: wave-uniform base + lane*16)
static __device__ __forceinline__ void gload_lds16(const float* g, void* l) {
    __builtin_amdgcn_global_load_lds(
        (const __attribute__((address_space(1))) uint32_t*)g,
        (__attribute__((address_space(3))) uint32_t*)l,
        16, 0, 0);
}

// ---------------------------------------------------------------------------
// Prologue: W_obj (f32 [k=256][t=256]) -> Wf, bf16 in MFMA fragment order.
// ---------------------------------------------------------------------------
__global__ void wconv_frag_kernel(const float* __restrict__ W, uint16_t* __restrict__ Wf) {
    int q = blockIdx.x * 256 + threadIdx.x;   // 8192 chunks of 16B
    int lane = q & 63;
    int s  = (q >> 6) & 7;
    int j  = (q >> 9) & 3;
    int wc = (q >> 11) & 3;
    int tcol = wc * 64 + j * 16 + (lane & 15);
    int k0   = s * 32 + (lane >> 4) * 8;
    uint4 w;
    unsigned p[4];
#pragma unroll
    for (int h = 0; h < 4; ++h) {
        float a = W[(size_t)(k0 + 2 * h)     * TOK + tcol];
        float b = W[(size_t)(k0 + 2 * h + 1) * TOK + tcol];
        p[h] = pack_bf16x2(a, b);
    }
    w.x = p[0]; w.y = p[1]; w.z = p[2]; w.w = p[3];
    *reinterpret_cast<uint4*>(Wf + (size_t)q * 8) = w;
}

// ---------------------------------------------------------------------------
// STREAM PROBE (diagnostic): exact gload_lds DMA structure, 5-buffer
// depth-4 pipeline, counted vmcnt, NO MFMA / NO cvt. Reads demo half 1
// (134 MB), writes the same bytes to the corresponding out rows (garbage
// values — fully overwritten by fused_kernel afterwards).
// ---------------------------------------------------------------------------
__global__ __launch_bounds__(256, 2) void stream_probe(
    const float* __restrict__ demo_obj, float* __restrict__ out)
{
    __shared__ __align__(16) float P[5][16 * TOK];   // 80 KB
    int ob = blockIdx.x;
    int h0 = ob * PRB_NG;
    int tid = threadIdx.x;

    auto STAGE = [&](int it, int bs) {
        const float* sb = demo_obj + (size_t)(h0 + it) * (16 * TOK);
        float* dst = &P[bs][0];
#pragma unroll
        for (int i = 0; i < 4; ++i) {
            int slot = i * 256 + tid;           // 1024 chunks of 16B
            gload_lds16(sb + (size_t)slot * 4, dst + (size_t)slot * 4);
        }
    };

    // prologue: 4 tiles (16 loads/wave) in flight
    STAGE(0, 0); STAGE(1, 1); STAGE(2, 2); STAGE(3, 3);

    int bc = 0;   // buffer of tile it
#pragma unroll 1
    for (int it = 0; it < PRB_NG; ++it) {
        // per-wave FIFO: 4L+4S per iter, 16L prologue.
        // it=0: newer-than-L0 = L1..L3 (12). it>=1: vmcnt(16) provably
        // retires L_{it+1} each step (induction from vmcnt(12) base).
        if (it == 0) asm volatile("s_waitcnt vmcnt(12)" ::: "memory");
        else         asm volatile("s_waitcnt vmcnt(16)" ::: "memory");
        __builtin_amdgcn_s_barrier();
        __builtin_amdgcn_sched_barrier(0);

        if (it + 4 < PRB_NG) {
            int bs = bc - 1; if (bs < 0) bs = 4;   // (it+4)%5 == (it-1)%5
            STAGE(it + 4, bs);
        }

        const float* buf = &P[bc][0];
        int h = h0 + it;
        int g = h >> 2, q = h & 3;
        int d = g >> 8, b = g & 255;
        int row_base = b * SEQ + 1 + d * (NOBJ + 1) + q * 16;
#pragma unroll
        for (int i = 0; i < 4; ++i) {
            int slot = i * 256 + tid;
            int r = slot >> 6, c = slot & 63;
            f32x4 v = *reinterpret_cast<const f32x4*>(buf + (size_t)slot * 4);
            *reinterpret_cast<f32x4*>(out + (size_t)(row_base + r) * TOK + c * 4) = v;
        }
        bc = (bc == 4) ? 0 : bc + 1;
    }
}

// ---------------------------------------------------------------------------
// Fused kernel — byte-identical to round 8 (known-good 172 us baseline).
// ---------------------------------------------------------------------------
__global__ __launch_bounds__(256, 2) void fused_kernel(
    const float* __restrict__ demo_obj,
    const float* __restrict__ cur,
    const float* __restrict__ b_obj,
    const __bf16* __restrict__ Wf,
    const float* __restrict__ demo_act,
    const float* __restrict__ W_act,
    const float* __restrict__ b_act,
    const float* __restrict__ instr,
    const float* __restrict__ W_instr,
    const float* __restrict__ b_instr,
    float* __restrict__ out)
{
    __shared__ __align__(16) float lds[2 * 32 * TOK];   // 64 KB
    int blk = blockIdx.x;
    int tid = threadIdx.x;

    if (blk >= ACT_BLKS + INSTR_BLKS) {
        int ob = blk - (ACT_BLKS + INSTR_BLKS);
        int h0 = ob * NG;
        const float* base = (h0 < 2 * NDG)
            ? demo_obj + (size_t)h0 * (32 * TOK)
            : cur + (size_t)(h0 - 2 * NDG) * (32 * TOK);

        int wave = tid >> 6, lane = tid & 63;
        int l15 = lane & 15, l4 = lane >> 4;
        int n0 = wave * 64;

        auto STAGE = [&](int it, int bsel) {
            const float* sb = base + (size_t)it * (32 * TOK);
            float* dst = lds + bsel * (32 * TOK);
#pragma unroll
            for (int i = 0; i < 8; ++i) {
                int r = i * 4 + wave;
                int gch = r * 64 + ((tid & 63) ^ (r & 7));
                gload_lds16(sb + (size_t)gch * 4, dst + (size_t)(i * 256 + tid) * 4);
            }
        };

        bf16x8 wf[4][8];
        {
            const __bf16* fb = Wf + ((size_t)wave * 32 * 64 + lane) * 8;
#pragma unroll
            for (int j = 0; j < 4; ++j)
#pragma unroll
                for (int s = 0; s < 8; ++s)
                    wf[j][s] = *reinterpret_cast<const bf16x8*>(fb + (size_t)(j * 8 + s) * 64 * 8);
        }
#pragma unroll
        for (int j = 0; j < 4; ++j)
#pragma unroll
            for (int s = 0; s < 8; ++s)
                asm volatile("" : "+v"(wf[j][s]));

        f32x4 bv4[4];
#pragma unroll
        for (int j = 0; j < 4; ++j) {
            bv4[j] = *reinterpret_cast<const f32x4*>(b_obj + n0 + j * 16 + l4 * 4);
            asm volatile("" : "+v"(bv4[j]));
        }

        STAGE(0, 0);
        STAGE(1, 1);

#pragma unroll 1
        for (int it = 0; it < NG; ++it) {
            asm volatile("s_waitcnt vmcnt(8)" ::: "memory");
            __builtin_amdgcn_s_barrier();
            __builtin_amdgcn_sched_barrier(0);

            if (it + 1 < NG) STAGE(it + 1, (it + 1) & 1);

            const float* buf = lds + (it & 1) * (32 * TOK);

            f32x4 acc[2][4];
#pragma unroll
            for (int i = 0; i < 2; ++i)
#pragma unroll
                for (int j = 0; j < 4; ++j) {
                    f32x4 z = {0.0f, 0.0f, 0.0f, 0.0f};
                    acc[i][j] = z;
                }

#pragma unroll
            for (int s = 0; s < 8; ++s) {
                bf16x8 a[2];
#pragma unroll
                for (int i = 0; i < 2; ++i) {
                    int r = i * 16 + l15;
                    int c0 = s * 8 + l4 * 2;
                    float4 lo = *reinterpret_cast<const float4*>(
                        buf + r * TOK + (size_t)((c0 ^ (r & 7)) * 4));
                    float4 hi = *reinterpret_cast<const float4*>(
                        buf + r * TOK + (size_t)(((c0 + 1) ^ (r & 7)) * 4));
                    a[i] = pack8n(lo, hi);
                }
#pragma unroll
                for (int j = 0; j < 4; ++j) {
                    acc[0][j] = __builtin_amdgcn_mfma_f32_16x16x32_bf16(wf[j][s], a[0], acc[0][j], 0, 0, 0);
                    acc[1][j] = __builtin_amdgcn_mfma_f32_16x16x32_bf16(wf[j][s], a[1], acc[1][j], 0, 0, 0);
                }
            }

            int h = h0 + it;
            int gg = h >> 1, half = h & 1;
            int row_base;
            if (h < 2 * NDG) {
                int d = gg >> 8, b = gg & 255;
                row_base = b * SEQ + 1 + d * (NOBJ + 1) + half * 32;
            } else {
                int b = gg - NDG;
                row_base = b * SEQ + 1 + NDEMO * (NOBJ + 1) + half * 32;
            }
#pragma unroll
            for (int i = 0; i < 2; ++i) {
                int row = row_base + i * 16 + l15;
#pragma unroll
                for (int j = 0; j < 4; ++j) {
                    f32x4 v = acc[i][j] + bv4[j];
                    *reinterpret_cast<f32x4*>(out + (size_t)row * TOK + n0 + j * 16 + l4 * 4) = v;
                }
            }
        }

    } else if (blk < ACT_BLKS) {
        int g8 = blk * 8;
        int t = tid;
        float v[8];
        float bb = b_act[t];
#pragma unroll
        for (int r = 0; r < 8; ++r) v[r] = bb;
#pragma unroll
        for (int k = 0; k < 7; ++k) {
            float wv = W_act[k * TOK + t];
#pragma unroll
            for (int r = 0; r < 8; ++r)
                v[r] += demo_act[(size_t)(g8 + r) * 7 + k] * wv;
        }
#pragma unroll
        for (int r = 0; r < 8; ++r) {
            int g = g8 + r;
            int d = g >> 8, b = g & 255;
            out[(size_t)(b * SEQ + (d + 1) * (NOBJ + 1)) * TOK + t] = v[r];
        }

    } else {
        int b0 = (blk - ACT_BLKS) * 2;
        int t = tid;
        float* buf = lds;
        const float* src = instr + (size_t)b0 * 768;
#pragma unroll
        for (int i = 0; i < 6; ++i) buf[i * 256 + t] = src[i * 256 + t];
        __syncthreads();
        float a0 = b_instr[t], a1 = a0;
#pragma unroll 4
        for (int k = 0; k < 768; ++k) {
            float wv = W_instr[(size_t)k * TOK + t];
            a0 += buf[k] * wv;
            a1 += buf[768 + k] * wv;
        }
        out[(size_t)b0 * SEQ * TOK + t] = a0;
        out[(size_t)(b0 + 1) * SEQ * TOK + t] = a1;
    }
}

extern "C" void kernel_launch(void* const* d_in, const int* in_sizes, int n_in,
                              void* d_out, int out_size, void* d_ws, size_t ws_size,
                              hipStream_t stream) {
    (void)in_sizes; (void)n_in; (void)out_size; (void)ws_size;
    const float* instr    = (const float*)d_in[0];
    const float* demo_obj = (const float*)d_in[1];
    const float* demo_act = (const float*)d_in[2];
    const float* cur      = (const float*)d_in[3];
    const float* W_instr  = (const float*)d_in[4];
    const float* b_instr  = (const float*)d_in[5];
    const float* W_act    = (const float*)d_in[6];
    const float* b_act    = (const float*)d_in[7];
    const float* W_obj    = (const float*)d_in[8];
    const float* b_obj    = (const float*)d_in[9];
    float* out = (float*)d_out;

    uint16_t* Wf = (uint16_t*)d_ws;   // 128 KB fragment-ordered bf16 weights

    wconv_frag_kernel<<<32, 256, 0, stream>>>(W_obj, Wf);
    // Diagnostic A: pure streaming through the exact DMA structure
    // (garbage output values — fully overwritten by fused_kernel below).
    stream_probe<<<PRB_BLKS, 256, 0, stream>>>(demo_obj, out);
    // Baseline B: round-8 kernel, computes ALL groups correctly.
    fused_kernel<<<TOTAL_BLKS, 256, 0, stream>>>(
        demo_obj, cur, b_obj, (const __bf16*)d_ws,
        demo_act, W_act, b_act, instr, W_instr, b_instr, out);
}

// Round 13
// 201.857 us; speedup vs baseline: 1.0466x; 1.0466x over previous
//
#include <hip/hip_runtime.h>
#include <hip/hip_bf16.h>
#include <stdint.h>

#define TOK   256
#define NOBJ  64
#define NDEMO 16
#define BATCH 256
#define SEQ   1105              /* 1 + 16*65 + 64 */
#define NDG   (NDEMO * BATCH)   /* 4096 demo groups */
#define NGRP  (NDG + BATCH)     /* 4352 total groups */
#define NQT   (NGRP * 4)        /* 17408 quarter-tiles (16 rows) */
#define QPB   16                /* quarter-tiles per obj block */
#define OBJ_BLKS   (NQT / QPB)  /* 1088; demo/cur boundary at block 1024 */
#define ACT_BLKS   512
#define INSTR_BLKS 128
#define TOTAL_BLKS (OBJ_BLKS + ACT_BLKS + INSTR_BLKS)

typedef __bf16 bf16x8 __attribute__((ext_vector_type(8)));
typedef float  f32x4  __attribute__((ext_vector_type(4)));

static __device__ __forceinline__ unsigned pack_bf16x2(float a, float b) {
    unsigned ua = __float_as_uint(a);
    unsigned ub = __float_as_uint(b);
    unsigned ra = (ua + 0x7FFFu + ((ua >> 16) & 1u)) >> 16;
    unsigned rb = (ub + 0x7FFFu + ((ub >> 16) & 1u)) >> 16;
    return (ra & 0xFFFFu) | (rb << 16);
}

static __device__ __forceinline__ bf16x8 pack8n(float4 lo, float4 hi) {
    bf16x8 o;
    o[0] = (__bf16)lo.x; o[1] = (__bf16)lo.y;
    o[2] = (__bf16)lo.z; o[3] = (__bf16)lo.w;
    o[4] = (__bf16)hi.x; o[5] = (__bf16)hi.y;
    o[6] = (__bf16)hi.z; o[7] = (__bf16)hi.w;
    return o;
}

// direct global->LDS, 16B/lane (dest linear: wave-uniform base + lane*16)
static __device__ __forceinline__ void gload_lds16(const float* g, void* l) {
    __builtin_amdgcn_global_load_lds(
        (const __attribute__((address_space(1))) uint32_t*)g,
        (__attribute__((address_space(3))) uint32_t*)l,
        16, 0, 0);
}

// ---------------------------------------------------------------------------
// Prologue: W_obj (f32 [k=256][t=256]) -> Wf, bf16 in MFMA fragment order:
// chunk q = ((wc*4 + j)*8 + s)*64 + lane  holds W[k = s*32+(lane>>4)*8 .. +7]
// [t = wc*64+j*16+(lane&15)] -- the A-operand (W^T) fragment stream.
// ---------------------------------------------------------------------------
__global__ void wconv_frag_kernel(const float* __restrict__ W, uint16_t* __restrict__ Wf) {
    int q = blockIdx.x * 256 + threadIdx.x;   // 8192 chunks of 16B
    int lane = q & 63;
    int s  = (q >> 6) & 7;
    int j  = (q >> 9) & 3;
    int wc = (q >> 11) & 3;
    int tcol = wc * 64 + j * 16 + (lane & 15);
    int k0   = s * 32 + (lane >> 4) * 8;
    uint4 w;
    unsigned p[4];
#pragma unroll
    for (int h = 0; h < 4; ++h) {
        float a = W[(size_t)(k0 + 2 * h)     * TOK + tcol];
        float b = W[(size_t)(k0 + 2 * h + 1) * TOK + tcol];
        p[h] = pack_bf16x2(a, b);
    }
    w.x = p[0]; w.y = p[1]; w.z = p[2]; w.w = p[3];
    *reinterpret_cast<uint4*>(Wf + (size_t)q * 8) = w;
}

// ---------------------------------------------------------------------------
// Fused kernel == round-12 stream_probe skeleton + MFMA compute.
//   [0, 1088)        : obj GEMM. 16-row quarter-tiles, 5-buffer depth-4
//                      gload_lds pipeline (proven 5.6 TB/s), per-wave
//                      L=4/S=4 per iter, tail-aware vmcnt 12/16/20/24.
//   [1088, 1600)     : action rows (8 per block)
//   [1600, 1728)     : instr rows (2 per block)
// ---------------------------------------------------------------------------
__global__ __launch_bounds__(256, 2) void fused_kernel(
    const float* __restrict__ demo_obj,   // (16,256,64,256)
    const float* __restrict__ cur,        // (256,64,256)
    const float* __restrict__ b_obj,      // (256,)
    const __bf16* __restrict__ Wf,        // fragment-ordered bf16 weights
    const float* __restrict__ demo_act,   // (16,256,7)
    const float* __restrict__ W_act,      // (7,256)
    const float* __restrict__ b_act,      // (256,)
    const float* __restrict__ instr,      // (256,768)
    const float* __restrict__ W_instr,    // (768,256)
    const float* __restrict__ b_instr,    // (256,)
    float* __restrict__ out)              // (256,1105,256)
{
    __shared__ __align__(16) float P[5][16 * TOK];   // 80 KB -> 2 blocks/CU
    int blk = blockIdx.x;
    int tid = threadIdx.x;

    if (blk < OBJ_BLKS) {
        // ================= obj GEMM =================
        int h0 = blk * QPB;   // blocks 0..1023 demo, 1024..1087 cur
        const float* base = (h0 < 4 * NDG)
            ? demo_obj + (size_t)h0 * (16 * TOK)
            : cur + (size_t)(h0 - 4 * NDG) * (16 * TOK);

        int wave = tid >> 6, lane = tid & 63;
        int l15 = lane & 15, l4 = lane >> 4;
        int n0 = wave * 64;   // this wave's 64 token columns

        auto STAGE = [&](int it, int bs) {
            const float* sb = base + (size_t)it * (16 * TOK);
            float* dst = &P[bs][0];
#pragma unroll
            for (int i = 0; i < 4; ++i) {
                int slot = i * 256 + tid;            // 1024 chunks of 16B
                int r = slot >> 6, c = slot & 63;
                gload_lds16(sb + (size_t)(r * 64 + (c ^ (r & 7))) * 4,
                            dst + (size_t)slot * 4);
            }
        };

        // ---- W preload (A-operand frags): 32 contiguous 1KB wave-loads ----
        bf16x8 wf[4][8];
        {
            const __bf16* fb = Wf + ((size_t)wave * 32 * 64 + lane) * 8;
#pragma unroll
            for (int j = 0; j < 4; ++j)
#pragma unroll
                for (int s = 0; s < 8; ++s)
                    wf[j][s] = *reinterpret_cast<const bf16x8*>(fb + (size_t)(j * 8 + s) * 64 * 8);
        }
#pragma unroll
        for (int j = 0; j < 4; ++j)
#pragma unroll
            for (int s = 0; s < 8; ++s)
                asm volatile("" : "+v"(wf[j][s]));   // wait lands in prologue

        f32x4 bv4[4];
#pragma unroll
        for (int j = 0; j < 4; ++j) {
            bv4[j] = *reinterpret_cast<const f32x4*>(b_obj + n0 + j * 16 + l4 * 4);
            asm volatile("" : "+v"(bv4[j]));
        }

        // ---- prologue: 4 tiles in flight (16 loads/wave) ----
        STAGE(0, 0); STAGE(1, 1); STAGE(2, 2); STAGE(3, 3);

        int bc = 0;   // buffer of tile it (= it % 5)
#pragma unroll 1
        for (int it = 0; it < QPB; ++it) {
            // newer-than-L_it in this wave's FIFO:
            //   loads  = 4*min(3, QPB-1-it), stores = 4*min(3, it)
            int nl = QPB - 1 - it; if (nl > 3) nl = 3;
            int ns = it;           if (ns > 3) ns = 3;
            int w = 4 * (nl + ns);
            if      (w >= 24) asm volatile("s_waitcnt vmcnt(24)" ::: "memory");
            else if (w == 20) asm volatile("s_waitcnt vmcnt(20)" ::: "memory");
            else if (w == 16) asm volatile("s_waitcnt vmcnt(16)" ::: "memory");
            else              asm volatile("s_waitcnt vmcnt(12)" ::: "memory");
            __builtin_amdgcn_s_barrier();
            __builtin_amdgcn_sched_barrier(0);

            // stage tile it+4 into buffer (it+4)%5 == (it-1)%5 (reads done)
            if (it + 4 < QPB) {
                int bs = bc - 1; if (bs < 0) bs = 4;
                STAGE(it + 4, bs);
            }

            const float* buf = &P[bc][0];

            f32x4 acc[4];
#pragma unroll
            for (int j = 0; j < 4; ++j) {
                f32x4 z = {0.0f, 0.0f, 0.0f, 0.0f};
                acc[j] = z;
            }

#pragma unroll
            for (int s = 0; s < 8; ++s) {
                int c0 = s * 8 + l4 * 2;
                float4 lo = *reinterpret_cast<const float4*>(
                    buf + l15 * TOK + (size_t)((c0 ^ (l15 & 7)) * 4));
                float4 hi = *reinterpret_cast<const float4*>(
                    buf + l15 * TOK + (size_t)(((c0 + 1) ^ (l15 & 7)) * 4));
                bf16x8 a = pack8n(lo, hi);
#pragma unroll
                for (int j = 0; j < 4; ++j)
                    acc[j] = __builtin_amdgcn_mfma_f32_16x16x32_bf16(wf[j][s], a, acc[j], 0, 0, 0);
            }

            // ---- epilogue: 4 f32x4 stores per lane (left in flight) ----
            int h = h0 + it;
            int g = h >> 2, q = h & 3;
            int row_base;
            if (h < 4 * NDG) {
                int d = g >> 8, b = g & 255;
                row_base = b * SEQ + 1 + d * (NOBJ + 1) + q * 16;
            } else {
                int b = g - NDG;
                row_base = b * SEQ + 1 + NDEMO * (NOBJ + 1) + q * 16;
            }
            int row = row_base + l15;
#pragma unroll
            for (int j = 0; j < 4; ++j) {
                f32x4 v = acc[j] + bv4[j];
                *reinterpret_cast<f32x4*>(out + (size_t)row * TOK + n0 + j * 16 + l4 * 4) = v;
            }

            bc = (bc == 4) ? 0 : bc + 1;
        }

    } else if (blk < OBJ_BLKS + ACT_BLKS) {
        // ================= action rows: 8 consecutive groups =================
        int g8 = (blk - OBJ_BLKS) * 8;
        int t = tid;
        float v[8];
        float bb = b_act[t];
#pragma unroll
        for (int r = 0; r < 8; ++r) v[r] = bb;
#pragma unroll
        for (int k = 0; k < 7; ++k) {
            float wv = W_act[k * TOK + t];
#pragma unroll
            for (int r = 0; r < 8; ++r)
                v[r] += demo_act[(size_t)(g8 + r) * 7 + k] * wv;
        }
#pragma unroll
        for (int r = 0; r < 8; ++r) {
            int g = g8 + r;
            int d = g >> 8, b = g & 255;
            out[(size_t)(b * SEQ + (d + 1) * (NOBJ + 1)) * TOK + t] = v[r];
        }

    } else {
        // ================= instr rows: 2 per block, K=768 =================
        int b0 = (blk - OBJ_BLKS - ACT_BLKS) * 2;
        int t = tid;
        float* buf = &P[0][0];   // 1536 f32 = 6 KB
        const float* src = instr + (size_t)b0 * 768;
#pragma unroll
        for (int i = 0; i < 6; ++i) buf[i * 256 + t] = src[i * 256 + t];
        __syncthreads();
        float a0 = b_instr[t], a1 = a0;
#pragma unroll 4
        for (int k = 0; k < 768; ++k) {
            float wv = W_instr[(size_t)k * TOK + t];
            a0 += buf[k] * wv;
            a1 += buf[768 + k] * wv;
        }
        out[(size_t)b0 * SEQ * TOK + t] = a0;
        out[(size_t)(b0 + 1) * SEQ * TOK + t] = a1;
    }
}

extern "C" void kernel_launch(void* const* d_in, const int* in_sizes, int n_in,
                              void* d_out, int out_size, void* d_ws, size_t ws_size,
                              hipStream_t stream) {
    (void)in_sizes; (void)n_in; (void)out_size; (void)ws_size;
    const float* instr    = (const float*)d_in[0];
    const float* demo_obj = (const float*)d_in[1];
    const float* demo_act = (const float*)d_in[2];
    const float* cur      = (const float*)d_in[3];
    const float* W_instr  = (const float*)d_in[4];
    const float* b_instr  = (const float*)d_in[5];
    const float* W_act    = (const float*)d_in[6];
    const float* b_act    = (const float*)d_in[7];
    const float* W_obj    = (const float*)d_in[8];
    const float* b_obj    = (const float*)d_in[9];
    float* out = (float*)d_out;

    uint16_t* Wf = (uint16_t*)d_ws;   // 128 KB fragment-ordered bf16 weights

    wconv_frag_kernel<<<32, 256, 0, stream>>>(W_obj, Wf);
    fused_kernel<<<TOTAL_BLKS, 256, 0, stream>>>(
        demo_obj, cur, b_obj, (const __bf16*)d_ws,
        demo_act, W_act, b_act, instr, W_instr, b_instr, out);
}